// Round 6
// baseline (2962.835 us; speedup 1.0000x reference)
//
#include <hip/hip_runtime.h>
#include <cstdint>
#include <cstddef>

#define BATCH 128
#define TLEN 4096
#define KS 64
#define NCHUNK 64  // chunk c covers t in [64c+1, min(64c+64, 4095)]

__device__ __forceinline__ float f3(float a, float b, float c) {
  return fmaxf(fmaxf(a, b), c);  // folds to v_max3_f32
}

// max over m[64] without clobbering m. 31 max3 + 1 fmax, depth 5.
// fp32 max returns an input bitwise, so any tree shape gives states
// bit-identical to the reference's pairwise max.
__device__ __forceinline__ float tree64(const float* m) {
  float t[22];
#pragma unroll
  for (int i = 0; i < 21; ++i) t[i] = f3(m[3 * i], m[3 * i + 1], m[3 * i + 2]);
  t[21] = m[63];
#pragma unroll
  for (int i = 0; i < 7; ++i) t[i] = f3(t[3 * i], t[3 * i + 1], t[3 * i + 2]);
  t[7] = t[21];
  t[0] = f3(t[0], t[1], t[2]);
  t[1] = f3(t[3], t[4], t[5]);
  t[2] = t[6];
  t[3] = t[7];
  t[0] = f3(t[0], t[1], t[2]);
  return fmaxf(t[0], t[3]);
}

// ---------------------------------------------------------------------------
// Forward recurrence. One wave per batch; LDS broadcast with no barrier
// (single-wave in-order LDS).
//
// Transition column lives in AGPRs: rounds 3-5 proved (VGPR_Count 72, pin
// no-op) that the compiler rematerializes const-__restrict__ trans loads
// inside the t-loop — 16 KB/step of L1 traffic (~256 cyc/step L1 BW) on the
// serial critical path. v_accvgpr_write via "a"-constraint asm is a real
// instruction the allocator can neither remat nor cheaply spill; in-loop
// reads are 2-cyc v_accvgpr_read VALU ops instead of L1 loads.
// ---------------------------------------------------------------------------
__global__ __launch_bounds__(64, 1) void crf_fwd(
    const float* __restrict__ pot, const float* __restrict__ trans,
    float* __restrict__ cp, float* __restrict__ fin) {
  const int b = blockIdx.x;
  const int j = threadIdx.x;
  __shared__ float4 sm4[KS / 4];
  float* sm = (float*)sm4;

  // pin transition column j into AGPRs
  float ca[KS];
#pragma unroll
  for (int i = 0; i < KS; ++i) {
    float v = trans[i * KS + j];
    asm volatile("v_accvgpr_write_b32 %0, %1" : "=a"(ca[i]) : "v"(v));
  }

  const float* pb = pot + (size_t)b * TLEN * KS + j;
  float* cpb = cp + (size_t)b * NCHUNK * KS + j;

  float s = pb[0];
  cpb[0] = s;
  sm[j] = s;

  // 4-deep emission prefetch ring (HBM latency ~900 cyc ≈ 2 steps)
  float ef[4];
#pragma unroll
  for (int q = 0; q < 4; ++q) ef[q] = pb[(size_t)(1 + q) * KS];

#pragma unroll 4
  for (int t = 1; t < TLEN; ++t) {
    float emit = ef[(t - 1) & 3];
    int tp = t + 4;
    tp = tp > TLEN - 1 ? TLEN - 1 : tp;
    ef[(t - 1) & 3] = pb[(size_t)tp * KS];

    // broadcast-read full state vector (same-address b128 reads: no
    // conflicts); add the AGPR-resident transition column.
    float m[KS];
#pragma unroll
    for (int q = 0; q < KS / 4; ++q) {
      float4 v = sm4[q];
      float c0, c1, c2, c3;
      asm volatile("v_accvgpr_read_b32 %0, %1" : "=v"(c0) : "a"(ca[4 * q + 0]));
      asm volatile("v_accvgpr_read_b32 %0, %1" : "=v"(c1) : "a"(ca[4 * q + 1]));
      asm volatile("v_accvgpr_read_b32 %0, %1" : "=v"(c2) : "a"(ca[4 * q + 2]));
      asm volatile("v_accvgpr_read_b32 %0, %1" : "=v"(c3) : "a"(ca[4 * q + 3]));
      m[4 * q + 0] = v.x + c0;
      m[4 * q + 1] = v.y + c1;
      m[4 * q + 2] = v.z + c2;
      m[4 * q + 3] = v.w + c3;
    }
    s = tree64(m) + emit;
    sm[j] = s;  // single-wave in-order LDS: next iteration's reads see this
    if ((t & 63) == 0) cpb[(size_t)(t >> 6) * KS] = s;
  }
  fin[(size_t)b * KS + j] = s;
}

// ---------------------------------------------------------------------------
// Backpointer reconstruction: per (batch, chunk) wave recomputes states from
// the checkpoint (bit-identical: fp32 max is exact, sums identical), derives
// bp[t][j] for all j, and fuses the speculative chunk-map chase via
// ds_bpermute. 8192 waves -> latency hidden by TLP; its L1 reloads are
// likewise hidden, so no AGPR pinning here (don't risk its occupancy).
// ---------------------------------------------------------------------------
__global__ __launch_bounds__(64) void crf_bp(
    const float* __restrict__ pot, const float* __restrict__ trans,
    const float* __restrict__ cp, unsigned char* __restrict__ bp,
    unsigned char* __restrict__ map) {
  const int b = blockIdx.x;
  const int ch = blockIdx.y;
  const int j = threadIdx.x;
  __shared__ float4 sm4[KS / 4];
  float* sm = (float*)sm4;

  float c[KS];
#pragma unroll
  for (int i = 0; i < KS; ++i) c[i] = trans[i * KS + j];

  float s = cp[((size_t)b * NCHUNK + ch) * KS + j];
  const int t0 = ch * 64;
  const int hi = min(t0 + 64, TLEN - 1);
  const float* pb = pot + (size_t)b * TLEN * KS + j;
  unsigned char* bpb = bp + (size_t)b * TLEN * KS + j;

  sm[j] = s;
  int tag = j;  // forward-composed backward map
  float emit = pb[(size_t)(t0 + 1) * KS];
  for (int t = t0 + 1; t <= hi; ++t) {
    float emit_next = pb[(size_t)min(t + 1, TLEN - 1) * KS];

    float m[KS];
#pragma unroll
    for (int q = 0; q < KS / 4; ++q) {
      float4 v = sm4[q];
      m[4 * q + 0] = v.x + c[4 * q + 0];
      m[4 * q + 1] = v.y + c[4 * q + 1];
      m[4 * q + 2] = v.z + c[4 * q + 2];
      m[4 * q + 3] = v.w + c[4 * q + 3];
    }
    float best = tree64(m);

    // first-occurrence argmax: descending exact-equality scan
    int bi = 63;
#pragma unroll
    for (int i = 62; i >= 0; --i) bi = (m[i] == best) ? i : bi;

    bpb[(size_t)t * KS] = (unsigned char)bi;
    s = best + emit;
    sm[j] = s;
    emit = emit_next;

    // g_t[k] = g_{t-1}[bp_t[k]]: lane k pulls lane bi_k's tag
    tag = __builtin_amdgcn_ds_bpermute(bi << 2, tag);
  }
  map[((size_t)b * NCHUNK + ch) * KS + j] = (unsigned char)tag;
}

// ---------------------------------------------------------------------------
// Compose chunk maps per batch (serial over 64 chunks, parallel over batches).
// Also does the final-state argmax (first-occurrence, strict >).
// ---------------------------------------------------------------------------
__global__ void crf_compose(const unsigned char* __restrict__ map,
                            const float* __restrict__ fin,
                            unsigned char* __restrict__ e,
                            int* __restrict__ tags_out) {
  const int b = blockIdx.x * blockDim.x + threadIdx.x;
  if (b >= BATCH) return;
  const float* fb = fin + (size_t)b * KS;
  float best = fb[0];
  int cur = 0;
  for (int i = 1; i < KS; ++i) {
    float v = fb[i];
    if (v > best) { best = v; cur = i; }
  }
  tags_out[(size_t)b * TLEN + (TLEN - 1)] = cur;
  for (int ch = NCHUNK - 1; ch >= 0; --ch) {
    e[(size_t)b * NCHUNK + ch] = (unsigned char)cur;
    cur = map[((size_t)b * NCHUNK + ch) * KS + cur];
  }
}

// ---------------------------------------------------------------------------
// Extract per-chunk paths from known entering tags (parallel over B*NCHUNK).
// ---------------------------------------------------------------------------
__global__ void crf_extract(const unsigned char* __restrict__ bp,
                            const unsigned char* __restrict__ e,
                            int* __restrict__ tags_out) {
  const int idx = blockIdx.x * blockDim.x + threadIdx.x;  // b*NCHUNK + c
  if (idx >= BATCH * NCHUNK) return;
  const int b = idx >> 6;
  const int c = idx & (NCHUNK - 1);
  const int lo = 64 * c + 1;
  const int hi = min(64 * c + 64, TLEN - 1);
  const unsigned char* bpb = bp + (size_t)b * TLEN * KS;
  int* to = tags_out + (size_t)b * TLEN;
  int tag = e[(size_t)b * NCHUNK + c];
  for (int t = hi; t >= lo; --t) {
    tag = bpb[(size_t)t * KS + tag];
    to[t - 1] = tag;
  }
}

// ---------------------------------------------------------------------------
// Sequence lengths = sum(mask) per batch.
// ---------------------------------------------------------------------------
__global__ __launch_bounds__(64) void crf_lens(const int* __restrict__ mask,
                                               int* __restrict__ out) {
  const int b = blockIdx.x;
  const int l = threadIdx.x;
  const int* mb = mask + (size_t)b * TLEN;
  int sum = 0;
  for (int t = l; t < TLEN; t += 64) sum += mb[t];
#pragma unroll
  for (int off = 32; off > 0; off >>= 1) sum += __shfl_down(sum, off, 64);
  if (l == 0) out[b] = sum;
}

extern "C" void kernel_launch(void* const* d_in, const int* in_sizes, int n_in,
                              void* d_out, int out_size, void* d_ws,
                              size_t ws_size, hipStream_t stream) {
  const float* pot = (const float*)d_in[0];    // (128, 4096, 64) fp32
  const float* trans = (const float*)d_in[1];  // (64, 64) fp32
  const int* mask = (const int*)d_in[2];       // (128, 4096) int32

  int* out = (int*)d_out;  // [tags: 128*4096][lens: 128]
  int* tags_out = out;
  int* lens_out = out + (size_t)BATCH * TLEN;

  // workspace layout
  char* w = (char*)d_ws;
  unsigned char* bp = (unsigned char*)w;                     // 33,554,432 B
  float* cp = (float*)(bp + (size_t)BATCH * TLEN * KS);      //  2,097,152 B
  float* fin = cp + (size_t)BATCH * NCHUNK * KS;             //     32,768 B
  unsigned char* map = (unsigned char*)(fin + (size_t)BATCH * KS);  // 524,288 B
  unsigned char* e = map + (size_t)BATCH * NCHUNK * KS;      //      8,192 B

  crf_fwd<<<BATCH, 64, 0, stream>>>(pot, trans, cp, fin);
  crf_lens<<<BATCH, 64, 0, stream>>>(mask, lens_out);
  crf_bp<<<dim3(BATCH, NCHUNK), 64, 0, stream>>>(pot, trans, cp, bp, map);
  crf_compose<<<1, BATCH, 0, stream>>>(map, fin, e, tags_out);
  crf_extract<<<(BATCH * NCHUNK + 255) / 256, 256, 0, stream>>>(bp, e, tags_out);
}

// Round 7
// 1917.437 us; speedup vs baseline: 1.5452x; 1.5452x over previous
//
#include <hip/hip_runtime.h>
#include <cstdint>
#include <cstddef>

#define BATCH 128
#define TLEN 4096
#define KS 64
#define NCHUNK 64  // chunk c covers t in [64c+1, min(64c+64, 4095)]

__device__ __forceinline__ float f3(float a, float b, float c) {
  return fmaxf(fmaxf(a, b), c);  // folds to v_max3_f32
}

// max over m[64] without clobbering m. 31 max3 + 1 fmax, depth 5.
// fp32 max returns an input bitwise, so any tree shape gives states
// bit-identical to the reference's pairwise max.
__device__ __forceinline__ float tree64(const float* m) {
  float t[22];
#pragma unroll
  for (int i = 0; i < 21; ++i) t[i] = f3(m[3 * i], m[3 * i + 1], m[3 * i + 2]);
  t[21] = m[63];
#pragma unroll
  for (int i = 0; i < 7; ++i) t[i] = f3(t[3 * i], t[3 * i + 1], t[3 * i + 2]);
  t[7] = t[21];
  t[0] = f3(t[0], t[1], t[2]);
  t[1] = f3(t[3], t[4], t[5]);
  t[2] = t[6];
  t[3] = t[7];
  t[0] = f3(t[0], t[1], t[2]);
  return fmaxf(t[0], t[3]);
}

// ---------------------------------------------------------------------------
// Forward recurrence. One wave per batch; LDS broadcast with no barrier
// (single-wave in-order LDS).
//
// Transition matrix lives in LDS (blocked i-major float4 layout:
// tl4[q*64+j] = {T[4q][j],T[4q+1][j],T[4q+2][j],T[4q+3][j]}, 16B-aligned,
// bank-spread). Rounds 3-6 proved the compiler remats const global trans
// loads inside the t-loop (16 KB/step of L1 on the serial chain) and that
// asm-pinning fights the scheduler. LDS re-reads are legal codegen we
// actually want: ~12 cyc per b128 at LDS BW floor, or hoisted to VGPRs.
// ---------------------------------------------------------------------------
__global__ __launch_bounds__(64, 1) void crf_fwd(
    const float* __restrict__ pot, const float* __restrict__ trans,
    float* __restrict__ cp, float* __restrict__ fin) {
  const int b = blockIdx.x;
  const int j = threadIdx.x;
  __shared__ float4 sm4[KS / 4];         // state broadcast (256 B)
  __shared__ float4 tl4[(KS / 4) * KS];  // transition tile (16 KB)
  float* sm = (float*)sm4;

  // preload transition tile: lane j fills its own column (coalesced loads)
#pragma unroll
  for (int q = 0; q < KS / 4; ++q) {
    float4 v;
    v.x = trans[(4 * q + 0) * KS + j];
    v.y = trans[(4 * q + 1) * KS + j];
    v.z = trans[(4 * q + 2) * KS + j];
    v.w = trans[(4 * q + 3) * KS + j];
    tl4[q * KS + j] = v;
  }
  // single wave -> in-order LDS; no barrier needed anywhere

  const float* pb = pot + (size_t)b * TLEN * KS + j;
  float* cpb = cp + (size_t)b * NCHUNK * KS + j;

  float s = pb[0];
  cpb[0] = s;
  sm[j] = s;

  // 4-deep emission prefetch ring (HBM latency ~900 cyc ≈ 2-3 steps)
  float ef[4];
#pragma unroll
  for (int q = 0; q < 4; ++q) ef[q] = pb[(size_t)(1 + q) * KS];

#pragma unroll 4
  for (int t = 1; t < TLEN; ++t) {
    float emit = ef[(t - 1) & 3];
    int tp = t + 4;
    tp = tp > TLEN - 1 ? TLEN - 1 : tp;
    ef[(t - 1) & 3] = pb[(size_t)tp * KS];

    // state broadcast (same-address b128) + LDS-resident transition column
    float m[KS];
#pragma unroll
    for (int q = 0; q < KS / 4; ++q) {
      float4 v = sm4[q];
      float4 c = tl4[q * KS + j];
      m[4 * q + 0] = v.x + c.x;
      m[4 * q + 1] = v.y + c.y;
      m[4 * q + 2] = v.z + c.z;
      m[4 * q + 3] = v.w + c.w;
    }
    s = tree64(m) + emit;
    sm[j] = s;  // single-wave in-order LDS: next iteration's reads see this
    if ((t & 63) == 0) cpb[(size_t)(t >> 6) * KS] = s;
  }
  fin[(size_t)b * KS + j] = s;
}

// ---------------------------------------------------------------------------
// Backpointer reconstruction: per (batch, chunk) wave recomputes states from
// the checkpoint (bit-identical: fp32 max is exact, sums identical), derives
// bp[t][j] for all j, and fuses the speculative chunk-map chase via
// ds_bpermute. 8192 waves -> latency hidden by TLP. (L1-BW-bound on trans
// reloads ~213 us floor; LDS-tiling redesign is a later round.)
// ---------------------------------------------------------------------------
__global__ __launch_bounds__(64) void crf_bp(
    const float* __restrict__ pot, const float* __restrict__ trans,
    const float* __restrict__ cp, unsigned char* __restrict__ bp,
    unsigned char* __restrict__ map) {
  const int b = blockIdx.x;
  const int ch = blockIdx.y;
  const int j = threadIdx.x;
  __shared__ float4 sm4[KS / 4];
  float* sm = (float*)sm4;

  float c[KS];
#pragma unroll
  for (int i = 0; i < KS; ++i) c[i] = trans[i * KS + j];

  float s = cp[((size_t)b * NCHUNK + ch) * KS + j];
  const int t0 = ch * 64;
  const int hi = min(t0 + 64, TLEN - 1);
  const float* pb = pot + (size_t)b * TLEN * KS + j;
  unsigned char* bpb = bp + (size_t)b * TLEN * KS + j;

  sm[j] = s;
  int tag = j;  // forward-composed backward map
  float emit = pb[(size_t)(t0 + 1) * KS];
  for (int t = t0 + 1; t <= hi; ++t) {
    float emit_next = pb[(size_t)min(t + 1, TLEN - 1) * KS];

    float m[KS];
#pragma unroll
    for (int q = 0; q < KS / 4; ++q) {
      float4 v = sm4[q];
      m[4 * q + 0] = v.x + c[4 * q + 0];
      m[4 * q + 1] = v.y + c[4 * q + 1];
      m[4 * q + 2] = v.z + c[4 * q + 2];
      m[4 * q + 3] = v.w + c[4 * q + 3];
    }
    float best = tree64(m);

    // first-occurrence argmax: descending exact-equality scan
    int bi = 63;
#pragma unroll
    for (int i = 62; i >= 0; --i) bi = (m[i] == best) ? i : bi;

    bpb[(size_t)t * KS] = (unsigned char)bi;
    s = best + emit;
    sm[j] = s;
    emit = emit_next;

    // g_t[k] = g_{t-1}[bp_t[k]]: lane k pulls lane bi_k's tag
    tag = __builtin_amdgcn_ds_bpermute(bi << 2, tag);
  }
  map[((size_t)b * NCHUNK + ch) * KS + j] = (unsigned char)tag;
}

// ---------------------------------------------------------------------------
// Compose chunk maps per batch (serial over 64 chunks, parallel over batches).
// Also does the final-state argmax (first-occurrence, strict >).
// ---------------------------------------------------------------------------
__global__ void crf_compose(const unsigned char* __restrict__ map,
                            const float* __restrict__ fin,
                            unsigned char* __restrict__ e,
                            int* __restrict__ tags_out) {
  const int b = blockIdx.x * blockDim.x + threadIdx.x;
  if (b >= BATCH) return;
  const float* fb = fin + (size_t)b * KS;
  float best = fb[0];
  int cur = 0;
  for (int i = 1; i < KS; ++i) {
    float v = fb[i];
    if (v > best) { best = v; cur = i; }
  }
  tags_out[(size_t)b * TLEN + (TLEN - 1)] = cur;
  for (int ch = NCHUNK - 1; ch >= 0; --ch) {
    e[(size_t)b * NCHUNK + ch] = (unsigned char)cur;
    cur = map[((size_t)b * NCHUNK + ch) * KS + cur];
  }
}

// ---------------------------------------------------------------------------
// Extract per-chunk paths from known entering tags (parallel over B*NCHUNK).
// ---------------------------------------------------------------------------
__global__ void crf_extract(const unsigned char* __restrict__ bp,
                            const unsigned char* __restrict__ e,
                            int* __restrict__ tags_out) {
  const int idx = blockIdx.x * blockDim.x + threadIdx.x;  // b*NCHUNK + c
  if (idx >= BATCH * NCHUNK) return;
  const int b = idx >> 6;
  const int c = idx & (NCHUNK - 1);
  const int lo = 64 * c + 1;
  const int hi = min(64 * c + 64, TLEN - 1);
  const unsigned char* bpb = bp + (size_t)b * TLEN * KS;
  int* to = tags_out + (size_t)b * TLEN;
  int tag = e[(size_t)b * NCHUNK + c];
  for (int t = hi; t >= lo; --t) {
    tag = bpb[(size_t)t * KS + tag];
    to[t - 1] = tag;
  }
}

// ---------------------------------------------------------------------------
// Sequence lengths = sum(mask) per batch.
// ---------------------------------------------------------------------------
__global__ __launch_bounds__(64) void crf_lens(const int* __restrict__ mask,
                                               int* __restrict__ out) {
  const int b = blockIdx.x;
  const int l = threadIdx.x;
  const int* mb = mask + (size_t)b * TLEN;
  int sum = 0;
  for (int t = l; t < TLEN; t += 64) sum += mb[t];
#pragma unroll
  for (int off = 32; off > 0; off >>= 1) sum += __shfl_down(sum, off, 64);
  if (l == 0) out[b] = sum;
}

extern "C" void kernel_launch(void* const* d_in, const int* in_sizes, int n_in,
                              void* d_out, int out_size, void* d_ws,
                              size_t ws_size, hipStream_t stream) {
  const float* pot = (const float*)d_in[0];    // (128, 4096, 64) fp32
  const float* trans = (const float*)d_in[1];  // (64, 64) fp32
  const int* mask = (const int*)d_in[2];       // (128, 4096) int32

  int* out = (int*)d_out;  // [tags: 128*4096][lens: 128]
  int* tags_out = out;
  int* lens_out = out + (size_t)BATCH * TLEN;

  // workspace layout
  char* w = (char*)d_ws;
  unsigned char* bp = (unsigned char*)w;                     // 33,554,432 B
  float* cp = (float*)(bp + (size_t)BATCH * TLEN * KS);      //  2,097,152 B
  float* fin = cp + (size_t)BATCH * NCHUNK * KS;             //     32,768 B
  unsigned char* map = (unsigned char*)(fin + (size_t)BATCH * KS);  // 524,288 B
  unsigned char* e = map + (size_t)BATCH * NCHUNK * KS;      //      8,192 B

  crf_fwd<<<BATCH, 64, 0, stream>>>(pot, trans, cp, fin);
  crf_lens<<<BATCH, 64, 0, stream>>>(mask, lens_out);
  crf_bp<<<dim3(BATCH, NCHUNK), 64, 0, stream>>>(pot, trans, cp, bp, map);
  crf_compose<<<1, BATCH, 0, stream>>>(map, fin, e, tags_out);
  crf_extract<<<(BATCH * NCHUNK + 255) / 256, 256, 0, stream>>>(bp, e, tags_out);
}